// Round 8
// baseline (184.322 us; speedup 1.0000x reference)
//
#include <hip/hip_runtime.h>

typedef _Float16 half8 __attribute__((ext_vector_type(8)));
typedef float floatx4 __attribute__((ext_vector_type(4)));
typedef float float4v __attribute__((ext_vector_type(4)));

#define AUNITS (64 * 13 * 24 * 64)    // 16B units in A'' (fragment-tiled image)
#define TUNITS (64 * 4 * 24 * 64)     // 16B units in B'' (fragment-tiled text)
#define A_HALFS ((size_t)AUNITS * 8)
#define BJ_HALFS (24 * 4 * 64 * 8)    // 49152 halfs per j
#define AI_HALFS (13 * 24 * 512)      // 159744 halfs per i

__device__ __forceinline__ void gl_lds16(const _Float16* g, _Float16* l) {
  __builtin_amdgcn_global_load_lds(
      (const __attribute__((address_space(1))) unsigned int*)g,
      (__attribute__((address_space(3))) unsigned int*)l, 16, 0, 0);
}

// ---------- repack: f32 -> f16 into MFMA-fragment-tiled layout ----------
// A''[i][tau][s][lane]{8}: lane l holds A_i[n=tau*16+(l&15)][d=s*32+(l>>4)*8..+7]
// B''[j][s][ct][lane]{8}:  lane l holds B_j[m=ct*16+(l&15)][d=s*32+(l>>4)*8..+7]
__global__ __launch_bounds__(256) void repack(const float* __restrict__ img,
                                              const float* __restrict__ txt,
                                              _Float16* __restrict__ Apk,
                                              _Float16* __restrict__ Bpk) {
  int gid = blockIdx.x * 256 + threadIdx.x;
  const float* src;
  _Float16* dst;
  if (gid < AUNITS) {
    int l = gid & 63, g = gid >> 6;
    int s = g % 24; g /= 24;
    int tau = g % 13; int i = g / 13;
    int n = tau * 16 + (l & 15); if (n > 195) n = 195;   // dup-pad rows 196..207
    src = img + (size_t)i * 197 * 768 + (size_t)(n + 1) * 768 + s * 32 + (l >> 4) * 8;
    dst = Apk + (size_t)gid * 8;
  } else {
    int u = gid - AUNITS;
    int l = u & 63, g = u >> 6;
    int ct = g & 3; g >>= 2;
    int s = g % 24; int j = g / 24;
    int m = ct * 16 + (l & 15);
    src = txt + (size_t)j * 65 * 768 + (size_t)(m + 1) * 768 + s * 32 + (l >> 4) * 8;
    dst = Bpk + (size_t)u * 8;
  }
  float4v v0 = *(const float4v*)src;
  float4v v1 = *(const float4v*)(src + 4);
  half8 h;
  h[0] = (_Float16)v0[0]; h[1] = (_Float16)v0[1]; h[2] = (_Float16)v0[2]; h[3] = (_Float16)v0[3];
  h[4] = (_Float16)v1[0]; h[5] = (_Float16)v1[1]; h[6] = (_Float16)v1[2]; h[7] = (_Float16)v1[3];
  *(half8*)dst = h;
}

// ---------- per-(i, j): 1 j per block, 4 waves, REGISTER B-DOUBLE-BUFFER ----
// r7 post-mortem: occupancy 2x'd with zero gain -> wall is the per-step
// per-wave chain {issue 4 ds_read -> wait -> 13 MFMA} exposing LDS latency on
// every wave every step (convoy). Fix: prefetch step s+1's B-frags into regs
// DURING step s's cluster (sc<3); cluster then starts with operands resident
// (compiler emits lgkmcnt(4), next-step reads stay in flight). Only 1-in-4
// chunk-boundary steps keep exposed LDS latency. No setprio: the win IS other
// waves issuing loads during this wave's cluster; prio fights that (m190).
// A: depth-1 global->reg, issued after the cluster. B: DMA chunk = 4 K-steps,
// 32 KB dbuf, counted vmcnt(16) handoff (16 a-loads newer than the 4 DMAs).
__global__ __launch_bounds__(256, 3) void sim_kernel(const _Float16* __restrict__ Apk,
                                                     const _Float16* __restrict__ Bpk,
                                                     const int* __restrict__ pm,
                                                     const float* __restrict__ ls,
                                                     float* __restrict__ lpi,
                                                     float* __restrict__ lpt) {
  __shared__ _Float16 Bsh[16384];           // [buf2][sc4][ct4][512 halfs] = 32 KB

  const int j = blockIdx.x, i = blockIdx.y;
  const int tid = threadIdx.x;
  const int wave = tid >> 6, lane = tid & 63;
  const int r16 = lane & 15;
  const int lane8 = lane * 8;

  const _Float16* Ai = Apk + (size_t)i * AI_HALFS;
  const _Float16* pA[4];
  pA[0] = Ai + (size_t)(wave)     * 24 * 512 + lane8;
  pA[1] = Ai + (size_t)(wave + 4) * 24 * 512 + lane8;
  pA[2] = Ai + (size_t)(wave + 8) * 24 * 512 + lane8;
  pA[3] = Ai + (size_t)12         * 24 * 512 + lane8;   // tile 12 (all waves)
  const _Float16* Bg = Bpk + (size_t)j * BJ_HALFS;

  // stage chunk cc (K-steps 4cc..4cc+3, 16 pieces x 1KB) : 4 pieces per wave
  auto stage = [&](int cc) {
    const int buf = cc & 1;
#pragma unroll
    for (int r4 = 0; r4 < 4; ++r4) {
      int rr = wave * 4 + r4;               // 0..15 = (sc = rr>>2, ct = rr&3)
      gl_lds16(Bg + (size_t)(4 * cc) * 2048 + rr * 512 + lane8,
               Bsh + buf * 8192 + rr * 512);
    }
  };

  // prologue: stage chunk 0 (4 DMA), then a(0) (4 loads) -> vmcnt(4) == DMA done
  stage(0);
  __builtin_amdgcn_sched_barrier(0);
  half8 af[4];
#pragma unroll
  for (int t = 0; t < 4; ++t) af[t] = *(const half8*)(pA[t]);
  __builtin_amdgcn_sched_barrier(0);
  asm volatile("s_waitcnt vmcnt(4)" ::: "memory");
  __builtin_amdgcn_s_barrier();
  __builtin_amdgcn_sched_barrier(0);

  floatx4 acc[3][4];
  floatx4 acc12 = (floatx4){0.f, 0.f, 0.f, 0.f};
#pragma unroll
  for (int t = 0; t < 3; ++t)
#pragma unroll
    for (int cc = 0; cc < 4; ++cc)
      acc[t][cc] = (floatx4){0.f, 0.f, 0.f, 0.f};

  half8 b[2][4];                            // register double-buffer for B-frags

#pragma unroll
  for (int c = 0; c < 6; ++c) {
    if (c > 0) {
      // handoff: since this wave's 4 chunk-DMAs, exactly 16 a-loads were
      // issued (4 per step) -> vmcnt(16) proves the DMAs retired. Counted
      // wait + raw barrier; a-prefetches keep flying.
      asm volatile("s_waitcnt vmcnt(16)" ::: "memory");
      __builtin_amdgcn_s_barrier();
      __builtin_amdgcn_sched_barrier(0);
    }

    // chunk-boundary: read this chunk's first B-frags (the 1-in-4 exposed read)
    {
      const int base = (c & 1) * 8192 + lane8;
#pragma unroll
      for (int cc = 0; cc < 4; ++cc) {
        int ct = (wave + cc) & 3;           // rotated: [0] is this wave's own group
        b[0][cc] = *(const half8*)(Bsh + base + ct * 512);
      }
    }
    if (c < 5) stage(c + 1);                // 4 DMAs fly during 4 steps of compute

#pragma unroll
    for (int sc = 0; sc < 4; ++sc) {
      const int s = c * 4 + sc;
      const int cur = sc & 1;

      // prefetch NEXT step's B-frags (same buffer) before this step's cluster;
      // the cluster only waits lgkmcnt(4) for its own (already-landed) frags.
      if (sc < 3) {
        const int nbase = (c & 1) * 8192 + (sc + 1) * 2048 + lane8;
#pragma unroll
        for (int cc = 0; cc < 4; ++cc) {
          int ct = (wave + cc) & 3;
          b[cur ^ 1][cc] = *(const half8*)(Bsh + nbase + ct * 512);
        }
      }

#pragma unroll
      for (int cc = 0; cc < 4; ++cc) {
        acc[0][cc] = __builtin_amdgcn_mfma_f32_16x16x32_f16(af[0], b[cur][cc], acc[0][cc], 0, 0, 0);
        acc[1][cc] = __builtin_amdgcn_mfma_f32_16x16x32_f16(af[1], b[cur][cc], acc[1][cc], 0, 0, 0);
        acc[2][cc] = __builtin_amdgcn_mfma_f32_16x16x32_f16(af[2], b[cur][cc], acc[2][cc], 0, 0, 0);
      }
      acc12 = __builtin_amdgcn_mfma_f32_16x16x32_f16(af[3], b[cur][0], acc12, 0, 0, 0);

      // depth-1 A-prefetch for step s+1, after the cluster (L2 latency hidden
      // by the other resident waves' clusters).
      if (s < 23) {
#pragma unroll
        for (int t = 0; t < 4; ++t) af[t] = *(const half8*)(pA[t] + (s + 1) * 512);
      }
      __builtin_amdgcn_sched_barrier(0);
    }
  }

  // ---------------- epilogue (verified in round 1) ----------------
  const float sgl = ls[0];
  bool msk[4];
  int colc[4];
#pragma unroll
  for (int cc = 0; cc < 4; ++cc) {
    colc[cc] = ((wave + cc) & 3) * 16 + r16;
    msk[cc] = pm[i * 65 + 1 + colc[cc]] != 0;
  }

  float rowsum = 0.f;
  float cmv[4];
#pragma unroll
  for (int t = 0; t < 3; ++t) {
#pragma unroll
    for (int r = 0; r < 4; ++r) {
      float rm = -__builtin_inff();
#pragma unroll
      for (int cc = 0; cc < 4; ++cc) {
        float v = acc[t][cc][r] * sgl;
        rm = fmaxf(rm, msk[cc] ? -__builtin_inff() : v);
      }
#pragma unroll
      for (int off = 1; off < 16; off <<= 1)
        rm = fmaxf(rm, __shfl_xor(rm, off, 64));
      rowsum += rm;
    }
  }
#pragma unroll
  for (int off = 1; off < 64; off <<= 1) rowsum += __shfl_xor(rowsum, off, 64);

  // per-column max over rows 0..191 (unmasked, per reference max_n)
#pragma unroll
  for (int cc = 0; cc < 4; ++cc) {
    float cm = -__builtin_inff();
#pragma unroll
    for (int t = 0; t < 3; ++t)
#pragma unroll
      for (int r = 0; r < 4; ++r)
        cm = fmaxf(cm, acc[t][cc][r] * sgl);
    cm = fmaxf(cm, __shfl_xor(cm, 16, 64));
    cm = fmaxf(cm, __shfl_xor(cm, 32, 64));
    cmv[cc] = cm;
  }

  __syncthreads();                          // all B reads done -> alias Bsh as scratch
  float* colmaxS = (float*)Bsh;             // [4][64]
  float* t12S    = (float*)Bsh + 256;       // [4][64]
  float* wsumS   = (float*)Bsh + 512;       // [4]

  if (lane == 0) wsumS[wave] = rowsum;
  if (lane < 16) {
#pragma unroll
    for (int cc = 0; cc < 4; ++cc) colmaxS[wave * 64 + colc[cc]] = cmv[cc];
#pragma unroll
    for (int r = 0; r < 4; ++r) t12S[r * 64 + wave * 16 + r16] = acc12[r] * sgl;
  }
  __syncthreads();

  if (tid < 64) {
    const int col = lane;
    bool valid = pm[i * 65 + 1 + col] == 0;
    float t0 = t12S[col], t1 = t12S[64 + col], t2 = t12S[128 + col], t3 = t12S[192 + col];
    float v = fmaxf(fmaxf(colmaxS[col], colmaxS[64 + col]),
                    fmaxf(colmaxS[128 + col], colmaxS[192 + col]));
    v = fmaxf(v, fmaxf(fmaxf(t0, t1), fmaxf(t2, t3)));       // full col max (n=0..195)
    float contrib = valid ? v : 0.f;
    float cntv = valid ? 1.f : 0.f;
    float rs0 = valid ? t0 : -__builtin_inff();
    float rs1 = valid ? t1 : -__builtin_inff();
    float rs2 = valid ? t2 : -__builtin_inff();
    float rs3 = valid ? t3 : -__builtin_inff();
#pragma unroll
    for (int off = 1; off < 64; off <<= 1) {
      contrib += __shfl_xor(contrib, off, 64);
      cntv += __shfl_xor(cntv, off, 64);
      rs0 = fmaxf(rs0, __shfl_xor(rs0, off, 64));
      rs1 = fmaxf(rs1, __shfl_xor(rs1, off, 64));
      rs2 = fmaxf(rs2, __shfl_xor(rs2, off, 64));
      rs3 = fmaxf(rs3, __shfl_xor(rs3, off, 64));
    }
    if (lane == 0) {
      lpt[i * 64 + j] = contrib / cntv;
      float wtot = wsumS[0] + wsumS[1] + wsumS[2] + wsumS[3];
      lpi[i * 64 + j] = (wtot * 0.0625f + rs0 + rs1 + rs2 + rs3) / 196.f;
    }
  }
}

// ---------------- CE losses + targets (2 waves: lpi & lpt in parallel) ------
// out layout: [0] loss | [1..4097) lpi | [4097..8193) lpt | [8193..8257) targets
__global__ __launch_bounds__(128) void ce_kernel(float* __restrict__ out) {
  __shared__ float part[2];
  const int tid = threadIdx.x;
  const int t = tid & 63;
  const float* src = (tid < 64) ? (out + 1) : (out + 1 + 4096);

  float mx = -__builtin_inff();
#pragma unroll
  for (int jj = 0; jj < 64; ++jj) mx = fmaxf(mx, src[t * 64 + jj]);
  float se = 0.f;
#pragma unroll
  for (int jj = 0; jj < 64; ++jj) se += __expf(src[t * 64 + jj] - mx);
  float v = (mx + __logf(se)) - src[t * 64 + t];

#pragma unroll
  for (int off = 1; off < 64; off <<= 1) v += __shfl_xor(v, off, 64);
  if (t == 0) part[tid >> 6] = v;
  __syncthreads();
  if (tid == 0) out[0] = 0.5f * (part[0] + part[1]) / 64.f;
  if (tid < 64) out[1 + 8192 + tid] = (float)tid;   // targets = arange(64)
}

extern "C" void kernel_launch(void* const* d_in, const int* in_sizes, int n_in,
                              void* d_out, int out_size, void* d_ws, size_t ws_size,
                              hipStream_t stream) {
  const float* image = (const float*)d_in[0];   // (64,197,768) f32
  const float* text  = (const float*)d_in[1];   // (64,65,768) f32
  const int*   pm    = (const int*)d_in[2];     // (64,65) i32
  const float* ls    = (const float*)d_in[3];   // scalar
  float* out = (float*)d_out;

  _Float16* Apk = (_Float16*)d_ws;              // fragment-tiled image
  _Float16* Bpk = Apk + A_HALFS;                // fragment-tiled text

  repack<<<(AUNITS + TUNITS) / 256, 256, 0, stream>>>(image, text, Apk, Bpk);

  dim3 grid(64, 64);   // x = j (fast): A_i stays L2-hot across consecutive blocks
  sim_kernel<<<grid, 256, 0, stream>>>(Apk, Bpk, pm, ls, out + 1, out + 1 + 4096);
  ce_kernel<<<1, 128, 0, stream>>>(out);
}

// Round 9
// 182.513 us; speedup vs baseline: 1.0099x; 1.0099x over previous
//
#include <hip/hip_runtime.h>

typedef _Float16 half8 __attribute__((ext_vector_type(8)));
typedef _Float16 half4 __attribute__((ext_vector_type(4)));
typedef float floatx4 __attribute__((ext_vector_type(4)));
typedef float float4v __attribute__((ext_vector_type(4)));

#define AUNITS (64 * 13 * 24 * 64)    // 16B units in A'' (fragment-tiled image)
#define TUNITS (64 * 4 * 24 * 64)     // 16B units in B'' (fragment-tiled text)
#define A_HALFS ((size_t)AUNITS * 8)
#define BJ_HALFS (24 * 4 * 64 * 8)    // 49152 halfs per j
#define AI_HALFS (13 * 24 * 512)      // 159744 halfs per i

__device__ __forceinline__ void gl_lds16(const _Float16* g, _Float16* l) {
  __builtin_amdgcn_global_load_lds(
      (const __attribute__((address_space(1))) unsigned int*)g,
      (__attribute__((address_space(3))) unsigned int*)l, 16, 0, 0);
}

// ---------- repack v2: coalesced read -> LDS transpose -> coalesced write ----
// Old repack read 64 scattered 32-B segments per wave (~4x line amplification,
// ~80 us hidden in the total). New: one block per 16-source-row tile.
//   A-blocks b in [0,832):  i = b/13, tau = b%13, rows n = tau*16+r (clamp 195)
//   B-blocks b in [832,1088): j = (b-832)/4, ct = (b-832)%4, rows m = ct*16+r
// Read: wave w handles rows 4w..4w+3; each row = 3 x (64 lanes x float4) = 3 KB
// fully coalesced. Cast to f16 into LDS [16][776] (776 = 768 + 8-half pad ->
// transpose reads are ~2-way conflict = free). Write: 1536 16-B units,
// 6/thread; unit u: s = u>>6, l = u&63 takes LDS[l&15][s*32+(l>>4)*8..+8];
// consecutive threads (same s) write consecutive 16 B -> 1 KB/wave coalesced.
// Output layout is IDENTICAL to v1 (sim unchanged):
//   A''[i][tau][s][lane]{8}: lane l holds A_i[n=tau*16+(l&15)][d=s*32+(l>>4)*8..+7]
//   B''[j][s][ct][lane]{8}:  lane l holds B_j[m=ct*16+(l&15)][d=s*32+(l>>4)*8..+7]
__global__ __launch_bounds__(256) void repack(const float* __restrict__ img,
                                              const float* __restrict__ txt,
                                              _Float16* __restrict__ Apk,
                                              _Float16* __restrict__ Bpk) {
  __shared__ _Float16 LT[16 * 776];         // 24.25 KB, padded rows

  const int b = blockIdx.x;
  const int tid = threadIdx.x;
  const int wave = tid >> 6, lane = tid & 63;

  const float* rowbase;                     // source row 0 (already +1 row offset)
  _Float16* dst;                            // this block's contiguous output
  int clampmax;                             // max row index to read (dup-pad)
  size_t unit_stride_ct = 0;                // 0 for A; B strides ct between s-units
  int ct = 0;

  if (b < 832) {
    int i = b / 13, tau = b % 13;
    rowbase = img + (size_t)i * 197 * 768 + 768 + (size_t)(tau * 16) * 768;
    clampmax = 195 - tau * 16;              // rows r > clampmax read row clampmax
    dst = Apk + (size_t)(i * 13 + tau) * (24 * 64 * 8);
  } else {
    int u = b - 832;
    int j = u >> 2; ct = u & 3;
    rowbase = txt + (size_t)j * 65 * 768 + 768 + (size_t)(ct * 16) * 768;
    clampmax = 15;                          // no clamp needed (m <= 63)
    dst = Bpk + ((size_t)j * 24 * 4 + ct) * (64 * 8);
    unit_stride_ct = 4 * 64 * 8;            // s-units stride by 4*1KB in B''
  }

  // ---- read 16 rows coalesced, cast, stage in LDS ----
#pragma unroll
  for (int rr = 0; rr < 4; ++rr) {
    int r = wave * 4 + rr;
    int rs = r > clampmax ? clampmax : r;   // dup-pad clamp (L1-hot re-read)
    const float* rp = rowbase + (size_t)rs * 768;
#pragma unroll
    for (int p = 0; p < 3; ++p) {
      float4v v = *(const float4v*)(rp + p * 256 + lane * 4);
      half4 h;
      h[0] = (_Float16)v[0]; h[1] = (_Float16)v[1];
      h[2] = (_Float16)v[2]; h[3] = (_Float16)v[3];
      *(half4*)(LT + r * 776 + p * 256 + lane * 4) = h;
    }
  }
  __syncthreads();

  // ---- emit 1536 fragment units (6 per thread), coalesced 16-B writes ----
#pragma unroll
  for (int k = 0; k < 6; ++k) {
    int u = tid + k * 256;                  // 0..1535
    int s = u >> 6, l = u & 63;
    half8 h = *(const half8*)(LT + (l & 15) * 776 + s * 32 + (l >> 4) * 8);
    _Float16* dp = (unit_stride_ct == 0)
                     ? (dst + (size_t)u * 8)
                     : (dst + (size_t)s * unit_stride_ct + (size_t)l * 8);
    *(half8*)dp = h;
  }
}

// ---------- per-(i, j): 1 j per block, 4 waves, 4 blocks/SIMD (r7 body) ----
// Grid is i-FAST: resident blocks {c, c+256, c+512, c+768} share i (256 == 0
// mod 64) -> their A-streams are identical -> served by L1/L2 instead of 4x L2
// traffic. Wave w owns row tiles {w, w+4, w+8} + column-group w of tile 12.
// A: global->reg depth-1 prefetch after the cluster. B: DMA chunk = 4 K-steps,
// 32 KB dbuf, counted vmcnt(16) handoff (16 a-loads newer than the 4 DMAs).
__global__ __launch_bounds__(256, 4) void sim_kernel(const _Float16* __restrict__ Apk,
                                                     const _Float16* __restrict__ Bpk,
                                                     const int* __restrict__ pm,
                                                     const float* __restrict__ ls,
                                                     float* __restrict__ lpi,
                                                     float* __restrict__ lpt) {
  __shared__ _Float16 Bsh[16384];           // [buf2][sc4][ct4][512 halfs] = 32 KB

  const int i = blockIdx.x, j = blockIdx.y; // i-fast (see header comment)
  const int tid = threadIdx.x;
  const int wave = tid >> 6, lane = tid & 63;
  const int r16 = lane & 15;
  const int lane8 = lane * 8;

  const _Float16* Ai = Apk + (size_t)i * AI_HALFS;
  const _Float16* pA[4];
  pA[0] = Ai + (size_t)(wave)     * 24 * 512 + lane8;
  pA[1] = Ai + (size_t)(wave + 4) * 24 * 512 + lane8;
  pA[2] = Ai + (size_t)(wave + 8) * 24 * 512 + lane8;
  pA[3] = Ai + (size_t)12         * 24 * 512 + lane8;   // tile 12 (all waves)
  const _Float16* Bg = Bpk + (size_t)j * BJ_HALFS;

  // stage chunk cc (K-steps 4cc..4cc+3, 16 pieces x 1KB) : 4 pieces per wave
  auto stage = [&](int cc) {
    const int buf = cc & 1;
#pragma unroll
    for (int r4 = 0; r4 < 4; ++r4) {
      int rr = wave * 4 + r4;               // 0..15 = (sc = rr>>2, ct = rr&3)
      gl_lds16(Bg + (size_t)(4 * cc) * 2048 + rr * 512 + lane8,
               Bsh + buf * 8192 + rr * 512);
    }
  };

  // prologue: stage chunk 0 (4 DMA), then a(0) (4 loads) -> vmcnt(4) == DMA done
  stage(0);
  __builtin_amdgcn_sched_barrier(0);
  half8 af[4];
#pragma unroll
  for (int t = 0; t < 4; ++t) af[t] = *(const half8*)(pA[t]);
  __builtin_amdgcn_sched_barrier(0);
  asm volatile("s_waitcnt vmcnt(4)" ::: "memory");
  __builtin_amdgcn_s_barrier();
  __builtin_amdgcn_sched_barrier(0);

  floatx4 acc[3][4];
  floatx4 acc12 = (floatx4){0.f, 0.f, 0.f, 0.f};
#pragma unroll
  for (int t = 0; t < 3; ++t)
#pragma unroll
    for (int cc = 0; cc < 4; ++cc)
      acc[t][cc] = (floatx4){0.f, 0.f, 0.f, 0.f};

#pragma unroll
  for (int c = 0; c < 6; ++c) {
#pragma unroll
    for (int sc = 0; sc < 4; ++sc) {
      const int s = c * 4 + sc;

      if (sc == 0 && c > 0) {
        // handoff: after this wave's last chunk-DMA, exactly 16 a-loads were
        // issued (4 per step of the previous chunk) -> vmcnt(16) proves all
        // DMA retired. Counted wait + raw barrier; prefetches keep flying.
        asm volatile("s_waitcnt vmcnt(16)" ::: "memory");
        __builtin_amdgcn_s_barrier();
        __builtin_amdgcn_sched_barrier(0);
      }

      // B-frags for THIS step from LDS
      const int base = (c & 1) * 8192 + sc * 2048 + lane8;
      half8 b[4];
#pragma unroll
      for (int cc = 0; cc < 4; ++cc) {
        int ct = (wave + cc) & 3;           // rotated: [0] is this wave's own group
        b[cc] = *(const half8*)(Bsh + base + ct * 512);
      }

      if (sc == 0 && c < 5) {               // issue next chunk's 4 DMAs now;
        stage(c + 1);                       // they fly during 4 steps of compute
        __builtin_amdgcn_sched_barrier(0);
      }

      __builtin_amdgcn_s_setprio(1);
#pragma unroll
      for (int cc = 0; cc < 4; ++cc) {
        acc[0][cc] = __builtin_amdgcn_mfma_f32_16x16x32_f16(af[0], b[cc], acc[0][cc], 0, 0, 0);
        acc[1][cc] = __builtin_amdgcn_mfma_f32_16x16x32_f16(af[1], b[cc], acc[1][cc], 0, 0, 0);
        acc[2][cc] = __builtin_amdgcn_mfma_f32_16x16x32_f16(af[2], b[cc], acc[2][cc], 0, 0, 0);
      }
      acc12 = __builtin_amdgcn_mfma_f32_16x16x32_f16(af[3], b[0], acc12, 0, 0, 0);
      __builtin_amdgcn_s_setprio(0);

      // depth-1 A-prefetch for step s+1, issued AFTER the cluster: its L1/L2
      // latency is hidden by the other 3 resident blocks on this SIMD.
      if (s < 23) {
#pragma unroll
        for (int t = 0; t < 4; ++t) af[t] = *(const half8*)(pA[t] + (s + 1) * 512);
      }
      __builtin_amdgcn_sched_barrier(0);
    }
  }

  // ---------------- epilogue (verified in round 1) ----------------
  const float sgl = ls[0];
  bool msk[4];
  int colc[4];
#pragma unroll
  for (int cc = 0; cc < 4; ++cc) {
    colc[cc] = ((wave + cc) & 3) * 16 + r16;
    msk[cc] = pm[i * 65 + 1 + colc[cc]] != 0;
  }

  float rowsum = 0.f;
  float cmv[4];
#pragma unroll
  for (int t = 0; t < 3; ++t) {
#pragma unroll
    for (int r = 0; r < 4; ++r) {
      float rm = -__builtin_inff();
#pragma unroll
      for (int cc = 0; cc < 4; ++cc) {
        float v = acc[t][cc][r] * sgl;
        rm = fmaxf(rm, msk[cc] ? -__builtin_inff() : v);
      }
#pragma unroll
      for (int off = 1; off < 16; off <<= 1)
        rm = fmaxf(rm, __shfl_xor(rm, off, 64));
      rowsum += rm;
    }
  }
#pragma unroll
  for (int off = 1; off < 64; off <<= 1) rowsum += __shfl_xor(rowsum, off, 64);

  // per-column max over rows 0..191 (unmasked, per reference max_n)
#pragma unroll
  for (int cc = 0; cc < 4; ++cc) {
    float cm = -__builtin_inff();
#pragma unroll
    for (int t = 0; t < 3; ++t)
#pragma unroll
      for (int r = 0; r < 4; ++r)
        cm = fmaxf(cm, acc[t][cc][r] * sgl);
    cm = fmaxf(cm, __shfl_xor(cm, 16, 64));
    cm = fmaxf(cm, __shfl_xor(cm, 32, 64));
    cmv[cc] = cm;
  }

  __syncthreads();                          // all B reads done -> alias Bsh as scratch
  float* colmaxS = (float*)Bsh;             // [4][64]
  float* t12S    = (float*)Bsh + 256;       // [4][64]
  float* wsumS   = (float*)Bsh + 512;       // [4]

  if (lane == 0) wsumS[wave] = rowsum;
  if (lane < 16) {
#pragma unroll
    for (int cc = 0; cc < 4; ++cc) colmaxS[wave * 64 + colc[cc]] = cmv[cc];
#pragma unroll
    for (int r = 0; r < 4; ++r) t12S[r * 64 + wave * 16 + r16] = acc12[r] * sgl;
  }
  __syncthreads();

  if (tid < 64) {
    const int col = lane;
    bool valid = pm[i * 65 + 1 + col] == 0;
    float t0 = t12S[col], t1 = t12S[64 + col], t2 = t12S[128 + col], t3 = t12S[192 + col];
    float v = fmaxf(fmaxf(colmaxS[col], colmaxS[64 + col]),
                    fmaxf(colmaxS[128 + col], colmaxS[192 + col]));
    v = fmaxf(v, fmaxf(fmaxf(t0, t1), fmaxf(t2, t3)));       // full col max (n=0..195)
    float contrib = valid ? v : 0.f;
    float cntv = valid ? 1.f : 0.f;
    float rs0 = valid ? t0 : -__builtin_inff();
    float rs1 = valid ? t1 : -__builtin_inff();
    float rs2 = valid ? t2 : -__builtin_inff();
    float rs3 = valid ? t3 : -__builtin_inff();
#pragma unroll
    for (int off = 1; off < 64; off <<= 1) {
      contrib += __shfl_xor(contrib, off, 64);
      cntv += __shfl_xor(cntv, off, 64);
      rs0 = fmaxf(rs0, __shfl_xor(rs0, off, 64));
      rs1 = fmaxf(rs1, __shfl_xor(rs1, off, 64));
      rs2 = fmaxf(rs2, __shfl_xor(rs2, off, 64));
      rs3 = fmaxf(rs3, __shfl_xor(rs3, off, 64));
    }
    if (lane == 0) {
      lpt[i * 64 + j] = contrib / cntv;
      float wtot = wsumS[0] + wsumS[1] + wsumS[2] + wsumS[3];
      lpi[i * 64 + j] = (wtot * 0.0625f + rs0 + rs1 + rs2 + rs3) / 196.f;
    }
  }
}

// ---------------- CE losses + targets (2 waves: lpi & lpt in parallel) ------
// out layout: [0] loss | [1..4097) lpi | [4097..8193) lpt | [8193..8257) targets
__global__ __launch_bounds__(128) void ce_kernel(float* __restrict__ out) {
  __shared__ float part[2];
  const int tid = threadIdx.x;
  const int t = tid & 63;
  const float* src = (tid < 64) ? (out + 1) : (out + 1 + 4096);

  float mx = -__builtin_inff();
#pragma unroll
  for (int jj = 0; jj < 64; ++jj) mx = fmaxf(mx, src[t * 64 + jj]);
  float se = 0.f;
#pragma unroll
  for (int jj = 0; jj < 64; ++jj) se += __expf(src[t * 64 + jj] - mx);
  float v = (mx + __logf(se)) - src[t * 64 + t];

#pragma unroll
  for (int off = 1; off < 64; off <<= 1) v += __shfl_xor(v, off, 64);
  if (t == 0) part[tid >> 6] = v;
  __syncthreads();
  if (tid == 0) out[0] = 0.5f * (part[0] + part[1]) / 64.f;
  if (tid < 64) out[1 + 8192 + tid] = (float)tid;   // targets = arange(64)
}

extern "C" void kernel_launch(void* const* d_in, const int* in_sizes, int n_in,
                              void* d_out, int out_size, void* d_ws, size_t ws_size,
                              hipStream_t stream) {
  const float* image = (const float*)d_in[0];   // (64,197,768) f32
  const float* text  = (const float*)d_in[1];   // (64,65,768) f32
  const int*   pm    = (const int*)d_in[2];     // (64,65) i32
  const float* ls    = (const float*)d_in[3];   // scalar
  float* out = (float*)d_out;

  _Float16* Apk = (_Float16*)d_ws;              // fragment-tiled image
  _Float16* Bpk = Apk + A_HALFS;                // fragment-tiled text

  repack<<<832 + 256, 256, 0, stream>>>(image, text, Apk, Bpk);

  dim3 grid(64, 64);   // x = i (fast): resident blocks share A_i (L1/L2-hot)
  sim_kernel<<<grid, 256, 0, stream>>>(Apk, Bpk, pm, ls, out + 1, out + 1 + 4096);
  ce_kernel<<<1, 128, 0, stream>>>(out);
}